// Round 1
// baseline (2484.389 us; speedup 1.0000x reference)
//
#include <hip/hip_runtime.h>

#define NNODES 50000
#define NEDGES 600000
#define DH 128

// ---------------- degree kernels ----------------
__global__ void deg_kernel(const int* __restrict__ src, const int* __restrict__ dst,
                           float* __restrict__ outdeg, float* __restrict__ indeg, int E) {
    int i = blockIdx.x * blockDim.x + threadIdx.x;
    if (i < E) {
        atomicAdd(&outdeg[src[i]], 1.0f);
        atomicAdd(&indeg[dst[i]], 1.0f);
    }
}

__global__ void inv_kernel(float* __restrict__ outdeg, float* __restrict__ indeg, int N) {
    int i = blockIdx.x * blockDim.x + threadIdx.x;
    if (i < N) {
        outdeg[i] = rsqrtf(fmaxf(outdeg[i], 1.0f));
        indeg[i]  = rsqrtf(fmaxf(indeg[i], 1.0f));
    }
}

// ---------------- SpMM: agg[dst] += h[src] * out_inv[src] ----------------
// one wave (64 lanes) per edge; each lane owns a float2 column pair
__global__ __launch_bounds__(256) void spmm_kernel(
        const float* __restrict__ h, const int* __restrict__ src,
        const int* __restrict__ dst, const float* __restrict__ out_inv,
        float* __restrict__ agg, int E) {
    int gw   = (blockIdx.x * blockDim.x + threadIdx.x) >> 6;
    int lane = threadIdx.x & 63;
    if (gw >= E) return;
    int s = src[gw];
    int d = dst[gw];
    float sc = out_inv[s];
    float2 v = ((const float2*)(h + (size_t)s * DH))[lane];
    float* ap = agg + (size_t)d * DH + 2 * lane;
    atomicAdd(ap,     v.x * sc);
    atomicAdd(ap + 1, v.y * sc);
}

// ---------------- hidden GEMM: Y = relu((X*in_inv) @ W + b) ----------------
// W (128x128, 64KB) staged in LDS; one wave per row; k-broadcast via shfl
template<int RELU>
__global__ __launch_bounds__(256) void gemm_h(
        const float* __restrict__ X, const float* __restrict__ in_inv,
        const float* __restrict__ W, const float* __restrict__ b,
        float* __restrict__ Y, int N) {
    __shared__ float Wl[DH * DH];
    for (int i = threadIdx.x; i < DH * DH / 4; i += blockDim.x)
        ((float4*)Wl)[i] = ((const float4*)W)[i];
    __syncthreads();

    int lane = threadIdx.x & 63;
    int wid  = threadIdx.x >> 6;
    int wpb  = blockDim.x >> 6;
    int gw   = blockIdx.x * wpb + wid;
    int nw   = gridDim.x * wpb;
    float2 bb = ((const float2*)b)[lane];

    for (int row = gw; row < N; row += nw) {
        float sc = in_inv[row];
        float2 x = ((const float2*)(X + (size_t)row * DH))[lane];
        x.x *= sc; x.y *= sc;
        float acc0 = bb.x, acc1 = bb.y;
#pragma unroll 8
        for (int kk = 0; kk < 64; ++kk) {
            float xa = __shfl(x.x, kk);
            float xb = __shfl(x.y, kk);
            float2 w0 = ((const float2*)(Wl + (2 * kk)     * DH))[lane];
            float2 w1 = ((const float2*)(Wl + (2 * kk + 1) * DH))[lane];
            acc0 += xa * w0.x + xb * w1.x;
            acc1 += xa * w0.y + xb * w1.y;
        }
        if (RELU) { acc0 = fmaxf(acc0, 0.f); acc1 = fmaxf(acc1, 0.f); }
        ((float2*)(Y + (size_t)row * DH))[lane] = make_float2(acc0, acc1);
    }
}

// ---------------- output GEMM: Y = (X*in_inv) @ W3 + b3 (128 -> 10) ----------------
__global__ __launch_bounds__(256) void gemm_out(
        const float* __restrict__ X, const float* __restrict__ in_inv,
        const float* __restrict__ W, const float* __restrict__ b,
        float* __restrict__ Y, int N) {
    __shared__ float Wl[DH * 10];
    for (int i = threadIdx.x; i < DH * 10; i += blockDim.x) Wl[i] = W[i];
    __syncthreads();

    int lane = threadIdx.x & 63;
    int wid  = threadIdx.x >> 6;
    int wpb  = blockDim.x >> 6;
    int gw   = blockIdx.x * wpb + wid;
    int nw   = gridDim.x * wpb;

    for (int row = gw; row < N; row += nw) {
        float sc = in_inv[row];
        float2 x = ((const float2*)(X + (size_t)row * DH))[lane];
        x.x *= sc; x.y *= sc;
        float acc[10];
#pragma unroll
        for (int o = 0; o < 10; ++o)
            acc[o] = x.x * Wl[(2 * lane) * 10 + o] + x.y * Wl[(2 * lane + 1) * 10 + o];
#pragma unroll
        for (int off = 32; off > 0; off >>= 1) {
#pragma unroll
            for (int o = 0; o < 10; ++o)
                acc[o] += __shfl_down(acc[o], off);
        }
        if (lane == 0) {
#pragma unroll
            for (int o = 0; o < 10; ++o)
                Y[(size_t)row * 10 + o] = acc[o] + b[o];
        }
    }
}

extern "C" void kernel_launch(void* const* d_in, const int* in_sizes, int n_in,
                              void* d_out, int out_size, void* d_ws, size_t ws_size,
                              hipStream_t stream) {
    const float* features = (const float*)d_in[0];
    const int*   src      = (const int*)d_in[1];
    const int*   dst      = (const int*)d_in[2];
    const float* W0 = (const float*)d_in[3];
    const float* b0 = (const float*)d_in[4];
    const float* W1 = (const float*)d_in[5];
    const float* b1 = (const float*)d_in[6];
    const float* W2 = (const float*)d_in[7];
    const float* b2 = (const float*)d_in[8];
    const float* W3 = (const float*)d_in[9];
    const float* b3 = (const float*)d_in[10];
    float* out = (float*)d_out;

    char* ws = (char*)d_ws;
    float* out_inv = (float*)ws;               // N floats
    float* in_inv  = out_inv + NNODES;         // N floats
    size_t degBytes = ((2 * NNODES * sizeof(float) + 255) / 256) * 256;
    float* bufA = (float*)(ws + degBytes);                 // N*DH floats
    float* bufB = bufA + (size_t)NNODES * DH;              // N*DH floats

    const size_t hBytes = (size_t)NNODES * DH * sizeof(float);

    // degrees -> inverse sqrt norms
    hipMemsetAsync(out_inv, 0, 2 * NNODES * sizeof(float), stream);
    deg_kernel<<<(NEDGES + 255) / 256, 256, 0, stream>>>(src, dst, out_inv, in_inv, NEDGES);
    inv_kernel<<<(NNODES + 255) / 256, 256, 0, stream>>>(out_inv, in_inv, NNODES);

    const int spmm_blocks = (NEDGES * 64) / 256;  // one wave per edge, 4 waves/block

    // Layer 0: features -> bufB
    hipMemsetAsync(bufA, 0, hBytes, stream);
    spmm_kernel<<<spmm_blocks, 256, 0, stream>>>(features, src, dst, out_inv, bufA, NEDGES);
    gemm_h<1><<<1024, 256, 0, stream>>>(bufA, in_inv, W0, b0, bufB, NNODES);

    // Layer 1: bufB -> bufB
    hipMemsetAsync(bufA, 0, hBytes, stream);
    spmm_kernel<<<spmm_blocks, 256, 0, stream>>>(bufB, src, dst, out_inv, bufA, NEDGES);
    gemm_h<1><<<1024, 256, 0, stream>>>(bufA, in_inv, W1, b1, bufB, NNODES);

    // Layer 2: bufB -> bufB
    hipMemsetAsync(bufA, 0, hBytes, stream);
    spmm_kernel<<<spmm_blocks, 256, 0, stream>>>(bufB, src, dst, out_inv, bufA, NEDGES);
    gemm_h<1><<<1024, 256, 0, stream>>>(bufA, in_inv, W2, b2, bufB, NNODES);

    // Layer 3: bufB -> out (128 -> 10, no relu)
    hipMemsetAsync(bufA, 0, hBytes, stream);
    spmm_kernel<<<spmm_blocks, 256, 0, stream>>>(bufB, src, dst, out_inv, bufA, NEDGES);
    gemm_out<<<512, 256, 0, stream>>>(bufA, in_inv, W3, b3, out, NNODES);
}

// Round 3
// 705.236 us; speedup vs baseline: 3.5228x; 3.5228x over previous
//
#include <hip/hip_runtime.h>

#define NNODES 50000
#define NEDGES 600000
#define DH 128

// ---------------- degree count (int atomics) ----------------
__global__ void deg_count(const int* __restrict__ src, const int* __restrict__ dst,
                          int* __restrict__ cnt_out, int* __restrict__ cnt_in, int E) {
    int i = blockIdx.x * blockDim.x + threadIdx.x;
    if (i < E) {
        atomicAdd(&cnt_out[src[i]], 1);
        atomicAdd(&cnt_in[dst[i]], 1);
    }
}

// ---------------- exclusive scan of cnt_in -> row_off (1 block, 1024 thr) ----------------
__global__ __launch_bounds__(1024) void scan_kernel(const int* __restrict__ counts,
                                                    int* __restrict__ off, int N) {
    __shared__ int sums[1024];
    int t = threadIdx.x;
    int chunk = (N + 1023) / 1024;
    int lo = t * chunk;
    int hi = lo + chunk; if (hi > N) hi = N;
    int s = 0;
    for (int i = lo; i < hi; ++i) s += counts[i];
    sums[t] = s;
    __syncthreads();
    for (int d = 1; d < 1024; d <<= 1) {
        int v = sums[t];
        int w = (t >= d) ? sums[t - d] : 0;
        __syncthreads();
        sums[t] = v + w;
        __syncthreads();
    }
    int run = (t == 0) ? 0 : sums[t - 1];
    for (int i = lo; i < hi; ++i) { off[i] = run; run += counts[i]; }
    if (hi == N) off[N] = run;
}

// ---------------- inverse-sqrt degree norms ----------------
__global__ void inv_kernel(const int* __restrict__ cnt_out, const int* __restrict__ cnt_in,
                           float* __restrict__ out_inv, float* __restrict__ in_inv, int N) {
    int i = blockIdx.x * blockDim.x + threadIdx.x;
    if (i < N) {
        out_inv[i] = rsqrtf(fmaxf((float)cnt_out[i], 1.0f));
        in_inv[i]  = rsqrtf(fmaxf((float)cnt_in[i], 1.0f));
    }
}

// ---------------- scatter edges into dst-CSR ----------------
__global__ void scatter_kernel(const int* __restrict__ src, const int* __restrict__ dst,
                               const int* __restrict__ row_off, int* __restrict__ cursor,
                               int* __restrict__ csr_src, int E) {
    int i = blockIdx.x * blockDim.x + threadIdx.x;
    if (i < E) {
        int d = dst[i];
        int pos = row_off[d] + atomicAdd(&cursor[d], 1);
        csr_src[pos] = src[i];
    }
}

// ---------------- SpMM (gather): agg[d] = in_inv[d] * sum_{s in N(d)} out_inv[s]*h[s] ----------------
// one wave per dst row; lane owns a float2 column pair; no atomics
__global__ __launch_bounds__(256) void spmm_csr(
        const float* __restrict__ h, const int* __restrict__ row_off,
        const int* __restrict__ csr_src, const float* __restrict__ out_inv,
        const float* __restrict__ in_inv, float* __restrict__ agg, int N) {
    int gw   = (blockIdx.x * blockDim.x + threadIdx.x) >> 6;
    int lane = threadIdx.x & 63;
    if (gw >= N) return;
    int start = row_off[gw], end = row_off[gw + 1];
    float accx = 0.f, accy = 0.f;
    for (int e = start; e < end; ++e) {
        int s = csr_src[e];
        float sc = out_inv[s];
        float2 v = ((const float2*)(h + (size_t)s * DH))[lane];
        accx += v.x * sc;
        accy += v.y * sc;
    }
    float ii = in_inv[gw];
    ((float2*)(agg + (size_t)gw * DH))[lane] = make_float2(accx * ii, accy * ii);
}

// ---------------- hidden GEMM: Y = relu(X @ W + b), 4 rows per wave ----------------
template<int RELU>
__global__ __launch_bounds__(256) void gemm_h(
        const float* __restrict__ X, const float* __restrict__ W,
        const float* __restrict__ b, float* __restrict__ Y, int N) {
    __shared__ float Wl[DH * DH];
    for (int i = threadIdx.x; i < DH * DH / 4; i += blockDim.x)
        ((float4*)Wl)[i] = ((const float4*)W)[i];
    __syncthreads();

    int lane = threadIdx.x & 63;
    int wid  = threadIdx.x >> 6;
    int grp  = blockIdx.x * 4 + wid;          // 4-row group id
    int row0 = grp * 4;
    if (row0 >= N) return;
    float2 bb = ((const float2*)b)[lane];

    float2 x[4];
#pragma unroll
    for (int r = 0; r < 4; ++r)
        x[r] = ((const float2*)(X + (size_t)(row0 + r) * DH))[lane];

    float2 acc[4];
#pragma unroll
    for (int r = 0; r < 4; ++r) acc[r] = bb;

#pragma unroll 4
    for (int kk = 0; kk < 64; ++kk) {
        float2 w0 = ((const float2*)(Wl + (2 * kk)     * DH))[lane];
        float2 w1 = ((const float2*)(Wl + (2 * kk + 1) * DH))[lane];
#pragma unroll
        for (int r = 0; r < 4; ++r) {
            float xa = __shfl(x[r].x, kk);
            float xb = __shfl(x[r].y, kk);
            acc[r].x += xa * w0.x + xb * w1.x;
            acc[r].y += xa * w0.y + xb * w1.y;
        }
    }
#pragma unroll
    for (int r = 0; r < 4; ++r) {
        float2 o = acc[r];
        if (RELU) { o.x = fmaxf(o.x, 0.f); o.y = fmaxf(o.y, 0.f); }
        ((float2*)(Y + (size_t)(row0 + r) * DH))[lane] = o;
    }
}

// ---------------- layer-3 projection: Z = (X * out_inv) @ W3   (N x 10) ----------------
__global__ __launch_bounds__(256) void proj_out(
        const float* __restrict__ X, const float* __restrict__ out_inv,
        const float* __restrict__ W, float* __restrict__ Z, int N) {
    __shared__ float Wl[DH * 10];
    for (int i = threadIdx.x; i < DH * 10; i += blockDim.x) Wl[i] = W[i];
    __syncthreads();

    int lane = threadIdx.x & 63;
    int wid  = threadIdx.x >> 6;
    int wpb  = blockDim.x >> 6;
    int gw   = blockIdx.x * wpb + wid;
    int nw   = gridDim.x * wpb;

    for (int row = gw; row < N; row += nw) {
        float sc = out_inv[row];
        float2 x = ((const float2*)(X + (size_t)row * DH))[lane];
        x.x *= sc; x.y *= sc;
        float acc[10];
#pragma unroll
        for (int o = 0; o < 10; ++o)
            acc[o] = x.x * Wl[(2 * lane) * 10 + o] + x.y * Wl[(2 * lane + 1) * 10 + o];
#pragma unroll
        for (int off = 32; off > 0; off >>= 1) {
#pragma unroll
            for (int o = 0; o < 10; ++o)
                acc[o] += __shfl_down(acc[o], off);
        }
        if (lane == 0) {
#pragma unroll
            for (int o = 0; o < 10; ++o)
                Z[(size_t)row * 10 + o] = acc[o];
        }
    }
}

// ---------------- layer-3 aggregation: out[d] = in_inv[d]*sum Z[s] + b3 ----------------
__global__ void agg10(const float* __restrict__ Z, const int* __restrict__ row_off,
                      const int* __restrict__ csr_src, const float* __restrict__ in_inv,
                      const float* __restrict__ b, float* __restrict__ out, int N) {
    int r = blockIdx.x * blockDim.x + threadIdx.x;
    if (r >= N) return;
    float2 acc[5] = {};
    int start = row_off[r], end = row_off[r + 1];
    for (int e = start; e < end; ++e) {
        int s = csr_src[e];
        const float2* zp = (const float2*)(Z + (size_t)s * 10);
#pragma unroll
        for (int o = 0; o < 5; ++o) {
            float2 z = zp[o];
            acc[o].x += z.x; acc[o].y += z.y;
        }
    }
    float ii = in_inv[r];
#pragma unroll
    for (int o = 0; o < 5; ++o) {
        out[(size_t)r * 10 + 2 * o]     = acc[o].x * ii + b[2 * o];
        out[(size_t)r * 10 + 2 * o + 1] = acc[o].y * ii + b[2 * o + 1];
    }
}

extern "C" void kernel_launch(void* const* d_in, const int* in_sizes, int n_in,
                              void* d_out, int out_size, void* d_ws, size_t ws_size,
                              hipStream_t stream) {
    const float* features = (const float*)d_in[0];
    const int*   src      = (const int*)d_in[1];
    const int*   dst      = (const int*)d_in[2];
    const float* W0 = (const float*)d_in[3];
    const float* b0 = (const float*)d_in[4];
    const float* W1 = (const float*)d_in[5];
    const float* b1 = (const float*)d_in[6];
    const float* W2 = (const float*)d_in[7];
    const float* b2 = (const float*)d_in[8];
    const float* W3 = (const float*)d_in[9];
    const float* b3 = (const float*)d_in[10];
    float* out = (float*)d_out;

    char* ws = (char*)d_ws;
    int*   cnt_out = (int*)ws;                       // N
    int*   cnt_in  = cnt_out + NNODES;               // N
    int*   cursor  = cnt_in + NNODES;                // N
    int*   row_off = cursor + NNODES;                // N+1
    float* out_inv = (float*)(row_off + NNODES + 1); // N
    float* in_inv  = out_inv + NNODES;               // N
    int*   csr_src = (int*)(in_inv + NNODES);        // E
    size_t metaInts = (size_t)(6 * NNODES + 1) + NEDGES;
    size_t metaBytes = ((metaInts * 4 + 255) / 256) * 256;
    float* bufA = (float*)(ws + metaBytes);          // N*DH
    float* bufB = bufA + (size_t)NNODES * DH;        // N*DH

    // ---- CSR build + norms (once per call) ----
    hipMemsetAsync(cnt_out, 0, 3 * NNODES * sizeof(int), stream);  // cnt_out, cnt_in, cursor
    deg_count<<<(NEDGES + 255) / 256, 256, 0, stream>>>(src, dst, cnt_out, cnt_in, NEDGES);
    scan_kernel<<<1, 1024, 0, stream>>>(cnt_in, row_off, NNODES);
    inv_kernel<<<(NNODES + 255) / 256, 256, 0, stream>>>(cnt_out, cnt_in, out_inv, in_inv, NNODES);
    scatter_kernel<<<(NEDGES + 255) / 256, 256, 0, stream>>>(src, dst, row_off, cursor, csr_src, NEDGES);

    const int spmm_blocks = (NNODES + 3) / 4;   // one wave per dst row
    const int gemm_blocks = (NNODES / 4 + 3) / 4;

    // Layer 0
    spmm_csr<<<spmm_blocks, 256, 0, stream>>>(features, row_off, csr_src, out_inv, in_inv, bufA, NNODES);
    gemm_h<1><<<gemm_blocks, 256, 0, stream>>>(bufA, W0, b0, bufB, NNODES);
    // Layer 1
    spmm_csr<<<spmm_blocks, 256, 0, stream>>>(bufB, row_off, csr_src, out_inv, in_inv, bufA, NNODES);
    gemm_h<1><<<gemm_blocks, 256, 0, stream>>>(bufA, W1, b1, bufB, NNODES);
    // Layer 2
    spmm_csr<<<spmm_blocks, 256, 0, stream>>>(bufB, row_off, csr_src, out_inv, in_inv, bufA, NNODES);
    gemm_h<1><<<gemm_blocks, 256, 0, stream>>>(bufA, W2, b2, bufB, NNODES);
    // Layer 3: project to O=10 first, then aggregate 10-wide
    proj_out<<<512, 256, 0, stream>>>(bufB, out_inv, W3, bufA, NNODES);   // Z = bufA (N x 10)
    agg10<<<(NNODES + 255) / 256, 256, 0, stream>>>(bufA, row_off, csr_src, in_inv, b3, out, NNODES);
}

// Round 6
// 429.015 us; speedup vs baseline: 5.7909x; 1.6439x over previous
//
#include <hip/hip_runtime.h>

#define NNODES 50000
#define NEDGES 600000
#define DH 128

typedef __attribute__((ext_vector_type(8))) short bf16x8;
typedef __attribute__((ext_vector_type(4))) float f32x4;

__device__ __forceinline__ ushort f2bf(float x) {
    uint u = __float_as_uint(x);
    uint r = (u + 0x7FFF + ((u >> 16) & 1)) >> 16;
    return (ushort)r;
}
__device__ __forceinline__ float bf2f(ushort h) {
    return __uint_as_float(((uint)h) << 16);
}

// ---------------- degree count (int atomics) ----------------
__global__ void deg_count(const int* __restrict__ src, const int* __restrict__ dst,
                          int* __restrict__ cnt_out, int* __restrict__ cnt_in, int E) {
    int i = blockIdx.x * blockDim.x + threadIdx.x;
    if (i < E) {
        atomicAdd(&cnt_out[src[i]], 1);
        atomicAdd(&cnt_in[dst[i]], 1);
    }
}

// ---------------- exclusive scan of cnt_in -> row_off ----------------
__global__ __launch_bounds__(1024) void scan_kernel(const int* __restrict__ counts,
                                                    int* __restrict__ off, int N) {
    __shared__ int sums[1024];
    int t = threadIdx.x;
    int chunk = (N + 1023) / 1024;
    int lo = t * chunk;
    int hi = lo + chunk; if (hi > N) hi = N;
    int s = 0;
    for (int i = lo; i < hi; ++i) s += counts[i];
    sums[t] = s;
    __syncthreads();
    for (int d = 1; d < 1024; d <<= 1) {
        int v = sums[t];
        int w = (t >= d) ? sums[t - d] : 0;
        __syncthreads();
        sums[t] = v + w;
        __syncthreads();
    }
    int run = (t == 0) ? 0 : sums[t - 1];
    for (int i = lo; i < hi; ++i) { off[i] = run; run += counts[i]; }
    if (hi == N) off[N] = run;
}

// ---------------- inverse-sqrt degree norms ----------------
__global__ void inv_kernel(const int* __restrict__ cnt_out, const int* __restrict__ cnt_in,
                           float* __restrict__ out_inv, float* __restrict__ in_inv, int N) {
    int i = blockIdx.x * blockDim.x + threadIdx.x;
    if (i < N) {
        out_inv[i] = rsqrtf(fmaxf((float)cnt_out[i], 1.0f));
        in_inv[i]  = rsqrtf(fmaxf((float)cnt_in[i], 1.0f));
    }
}

// ---------------- scatter edges into dst-CSR ----------------
__global__ void scatter_kernel(const int* __restrict__ src, const int* __restrict__ dst,
                               const int* __restrict__ row_off, int* __restrict__ cursor,
                               int* __restrict__ csr_src, int E) {
    int i = blockIdx.x * blockDim.x + threadIdx.x;
    if (i < E) {
        int d = dst[i];
        int pos = row_off[d] + atomicAdd(&cursor[d], 1);
        csr_src[pos] = src[i];
    }
}

// ---------------- W -> transposed bf16 hi/lo: WT[n][k] ----------------
__global__ void wconv(const float* __restrict__ W0, const float* __restrict__ W1,
                      const float* __restrict__ W2,
                      ushort* __restrict__ WThi, ushort* __restrict__ WTlo) {
    int t = blockIdx.x * blockDim.x + threadIdx.x;
    if (t >= 3 * DH * DH) return;
    int L = t >> 14;
    int idx = t & (DH * DH - 1);
    int n = idx >> 7;
    int k = idx & 127;
    const float* W = (L == 0) ? W0 : ((L == 1) ? W1 : W2);
    float w = W[k * DH + n];
    ushort hi = f2bf(w);
    float lof = w - bf2f(hi);
    WThi[t] = hi;              // t = L*16384 + n*128 + k
    WTlo[t] = f2bf(lof);
}

// ---------------- SpMM (gather), half-wave per dst row ----------------
// agg[d] = in_inv[d] * sum_{s in N(d)} out_inv[s]*h[s]; emits bf16 hi/lo
__global__ __launch_bounds__(256) void spmm_csr(
        const float* __restrict__ h, const int* __restrict__ row_off,
        const int* __restrict__ csr_src, const float* __restrict__ out_inv,
        const float* __restrict__ in_inv,
        ushort* __restrict__ Xhi, ushort* __restrict__ Xlo, int N) {
    int gw   = (blockIdx.x * blockDim.x + threadIdx.x) >> 6;
    int lane = threadIdx.x & 63;
    int half = lane >> 5;          // two rows per wave
    int l5   = lane & 31;          // 32 lanes x float4 = 512B row
    int row  = gw * 2 + half;
    if (row >= N) return;
    int start = row_off[row], end = row_off[row + 1];
    float4 acc = make_float4(0.f, 0.f, 0.f, 0.f);
    for (int e = start; e < end; ++e) {
        int s = csr_src[e];
        float sc = out_inv[s];
        float4 v = ((const float4*)(h + (size_t)s * DH))[l5];
        acc.x += v.x * sc; acc.y += v.y * sc;
        acc.z += v.z * sc; acc.w += v.w * sc;
    }
    float ii = in_inv[row];
    acc.x *= ii; acc.y *= ii; acc.z *= ii; acc.w *= ii;

    ushort4 hi, lo;
    hi.x = f2bf(acc.x); lo.x = f2bf(acc.x - bf2f(hi.x));
    hi.y = f2bf(acc.y); lo.y = f2bf(acc.y - bf2f(hi.y));
    hi.z = f2bf(acc.z); lo.z = f2bf(acc.z - bf2f(hi.z));
    hi.w = f2bf(acc.w); lo.w = f2bf(acc.w - bf2f(hi.w));
    ((ushort4*)(Xhi + (size_t)row * DH))[l5] = hi;
    ((ushort4*)(Xlo + (size_t)row * DH))[l5] = lo;
}

// ---------------- MFMA GEMM: Y = relu(X @ W + b), split-bf16 3-pass ----------------
// wave handles a 64-col half of W (B-frags persistent in registers),
// grid-strides over 16-row m-tiles. No LDS.
template<int RELU>
__global__ __launch_bounds__(256, 2) void gemm_mfma(
        const ushort* __restrict__ Xhi, const ushort* __restrict__ Xlo,
        const ushort* __restrict__ WThi, const ushort* __restrict__ WTlo,
        const float* __restrict__ bias, float* __restrict__ Y, int Mtiles) {
    int lane  = threadIdx.x & 63;
    int gwave = (blockIdx.x * blockDim.x + threadIdx.x) >> 6;
    int nwav  = (gridDim.x * blockDim.x) >> 6;
    int nhalf = gwave & 1;          // col half: 0 -> 0..63, 1 -> 64..127
    int wstart  = gwave >> 1;
    int wstride = nwav >> 1;

    int r  = lane & 15;             // A-row / B-col / D-col within tile
    int kq = lane >> 4;             // k quarter within a K=32 fragment

    // persistent B fragments: [hi/lo][ntile][kfrag]
    bf16x8 B[2][4][4];
    const ushort* wt0 = WThi;
    const ushort* wt1 = WTlo;
#pragma unroll
    for (int nt = 0; nt < 4; ++nt) {
        int n = 64 * nhalf + 16 * nt + r;
#pragma unroll
        for (int kf = 0; kf < 4; ++kf) {
            B[0][nt][kf] = *(const bf16x8*)(wt0 + n * DH + 32 * kf + 8 * kq);
            B[1][nt][kf] = *(const bf16x8*)(wt1 + n * DH + 32 * kf + 8 * kq);
        }
    }
    float bs[4];
#pragma unroll
    for (int nt = 0; nt < 4; ++nt) bs[nt] = bias[64 * nhalf + 16 * nt + r];

    for (int mt = wstart; mt < Mtiles; mt += wstride) {
        int m0 = mt * 16;
        const ushort* xh = Xhi + (size_t)(m0 + r) * DH + 8 * kq;
        const ushort* xl = Xlo + (size_t)(m0 + r) * DH + 8 * kq;
        bf16x8 Ah[4], Al[4];
#pragma unroll
        for (int kf = 0; kf < 4; ++kf) {
            Ah[kf] = *(const bf16x8*)(xh + 32 * kf);
            Al[kf] = *(const bf16x8*)(xl + 32 * kf);
        }
        f32x4 acc[4];
#pragma unroll
        for (int nt = 0; nt < 4; ++nt)
            acc[nt] = (f32x4){bs[nt], bs[nt], bs[nt], bs[nt]};
#pragma unroll
        for (int kf = 0; kf < 4; ++kf) {
#pragma unroll
            for (int nt = 0; nt < 4; ++nt) {
                acc[nt] = __builtin_amdgcn_mfma_f32_16x16x32_bf16(Ah[kf], B[0][nt][kf], acc[nt], 0, 0, 0);
                acc[nt] = __builtin_amdgcn_mfma_f32_16x16x32_bf16(Ah[kf], B[1][nt][kf], acc[nt], 0, 0, 0);
                acc[nt] = __builtin_amdgcn_mfma_f32_16x16x32_bf16(Al[kf], B[0][nt][kf], acc[nt], 0, 0, 0);
            }
        }
        // D: row = m0 + 4*kq + j, col = 64*nhalf + 16*nt + r
#pragma unroll
        for (int nt = 0; nt < 4; ++nt) {
            int n = 64 * nhalf + 16 * nt + r;
            float* yp = Y + (size_t)(m0 + 4 * kq) * DH + n;
#pragma unroll
            for (int j = 0; j < 4; ++j) {
                float v = acc[nt][j];
                if (RELU) v = fmaxf(v, 0.f);
                yp[(size_t)j * DH] = v;
            }
        }
    }
}

// ---------------- layer-3 projection: Z = (X * out_inv) @ W3   (N x 10) ----------------
__global__ __launch_bounds__(256) void proj_out(
        const float* __restrict__ X, const float* __restrict__ out_inv,
        const float* __restrict__ W, float* __restrict__ Z, int N) {
    __shared__ float Wl[DH * 10];
    for (int i = threadIdx.x; i < DH * 10; i += blockDim.x) Wl[i] = W[i];
    __syncthreads();

    int lane = threadIdx.x & 63;
    int wid  = threadIdx.x >> 6;
    int wpb  = blockDim.x >> 6;
    int gw   = blockIdx.x * wpb + wid;
    int nw   = gridDim.x * wpb;

    for (int row = gw; row < N; row += nw) {
        float sc = out_inv[row];
        float2 x = ((const float2*)(X + (size_t)row * DH))[lane];
        x.x *= sc; x.y *= sc;
        float acc[10];
#pragma unroll
        for (int o = 0; o < 10; ++o)
            acc[o] = x.x * Wl[(2 * lane) * 10 + o] + x.y * Wl[(2 * lane + 1) * 10 + o];
#pragma unroll
        for (int off = 32; off > 0; off >>= 1) {
#pragma unroll
            for (int o = 0; o < 10; ++o)
                acc[o] += __shfl_down(acc[o], off);
        }
        if (lane == 0) {
#pragma unroll
            for (int o = 0; o < 10; ++o)
                Z[(size_t)row * 10 + o] = acc[o];
        }
    }
}

// ---------------- layer-3 aggregation: out[d] = in_inv[d]*sum Z[s] + b3 ----------------
__global__ void agg10(const float* __restrict__ Z, const int* __restrict__ row_off,
                      const int* __restrict__ csr_src, const float* __restrict__ in_inv,
                      const float* __restrict__ b, float* __restrict__ out, int N) {
    int r = blockIdx.x * blockDim.x + threadIdx.x;
    if (r >= N) return;
    float2 acc[5] = {};
    int start = row_off[r], end = row_off[r + 1];
    for (int e = start; e < end; ++e) {
        int s = csr_src[e];
        const float2* zp = (const float2*)(Z + (size_t)s * 10);
#pragma unroll
        for (int o = 0; o < 5; ++o) {
            float2 z = zp[o];
            acc[o].x += z.x; acc[o].y += z.y;
        }
    }
    float ii = in_inv[r];
#pragma unroll
    for (int o = 0; o < 5; ++o) {
        out[(size_t)r * 10 + 2 * o]     = acc[o].x * ii + b[2 * o];
        out[(size_t)r * 10 + 2 * o + 1] = acc[o].y * ii + b[2 * o + 1];
    }
}

extern "C" void kernel_launch(void* const* d_in, const int* in_sizes, int n_in,
                              void* d_out, int out_size, void* d_ws, size_t ws_size,
                              hipStream_t stream) {
    const float* features = (const float*)d_in[0];
    const int*   src      = (const int*)d_in[1];
    const int*   dst      = (const int*)d_in[2];
    const float* W0 = (const float*)d_in[3];
    const float* b0 = (const float*)d_in[4];
    const float* W1 = (const float*)d_in[5];
    const float* b1 = (const float*)d_in[6];
    const float* W2 = (const float*)d_in[7];
    const float* b2 = (const float*)d_in[8];
    const float* W3 = (const float*)d_in[9];
    const float* b3 = (const float*)d_in[10];
    float* out = (float*)d_out;

    char* ws = (char*)d_ws;
    int*   cnt_out = (int*)ws;                       // N
    int*   cnt_in  = cnt_out + NNODES;               // N
    int*   cursor  = cnt_in + NNODES;                // N
    int*   row_off = cursor + NNODES;                // N+1
    float* out_inv = (float*)(row_off + NNODES + 1); // N
    float* in_inv  = out_inv + NNODES;               // N
    int*   csr_src = (int*)(in_inv + NNODES);        // E
    size_t metaInts = (size_t)(6 * NNODES + 1) + NEDGES;
    size_t off = ((metaInts * 4 + 255) / 256) * 256;
    ushort* WThi = (ushort*)(ws + off);  off += 3 * DH * DH * sizeof(ushort);
    ushort* WTlo = (ushort*)(ws + off);  off += 3 * DH * DH * sizeof(ushort);
    off = ((off + 255) / 256) * 256;
    ushort* Xhi = (ushort*)(ws + off);   off += (size_t)NNODES * DH * sizeof(ushort);
    ushort* Xlo = (ushort*)(ws + off);   off += (size_t)NNODES * DH * sizeof(ushort);
    float*  Y   = (float*)(ws + off);    off += (size_t)NNODES * DH * sizeof(float);
    float*  Z   = (float*)Xhi;           // reused for layer-3 projection (N x 10)

    // ---- CSR build + norms + W conversion (once per call) ----
    hipMemsetAsync(cnt_out, 0, 3 * NNODES * sizeof(int), stream);
    deg_count<<<(NEDGES + 255) / 256, 256, 0, stream>>>(src, dst, cnt_out, cnt_in, NEDGES);
    scan_kernel<<<1, 1024, 0, stream>>>(cnt_in, row_off, NNODES);
    inv_kernel<<<(NNODES + 255) / 256, 256, 0, stream>>>(cnt_out, cnt_in, out_inv, in_inv, NNODES);
    scatter_kernel<<<(NEDGES + 255) / 256, 256, 0, stream>>>(src, dst, row_off, cursor, csr_src, NEDGES);
    wconv<<<(3 * DH * DH + 255) / 256, 256, 0, stream>>>(W0, W1, W2, WThi, WTlo);

    const int spmm_blocks = (NNODES / 2 + 3) / 4;   // half-wave per row, 4 waves/block
    const int Mtiles = NNODES / 16;                 // 3125
    const int gemm_blocks = 512;                    // 2048 waves, persistent B-frags

    // Layer 0
    spmm_csr<<<spmm_blocks, 256, 0, stream>>>(features, row_off, csr_src, out_inv, in_inv, Xhi, Xlo, NNODES);
    gemm_mfma<1><<<gemm_blocks, 256, 0, stream>>>(Xhi, Xlo, WThi, WTlo, b0, Y, Mtiles);
    // Layer 1
    spmm_csr<<<spmm_blocks, 256, 0, stream>>>(Y, row_off, csr_src, out_inv, in_inv, Xhi, Xlo, NNODES);
    gemm_mfma<1><<<gemm_blocks, 256, 0, stream>>>(Xhi, Xlo, WThi + DH * DH, WTlo + DH * DH, b1, Y, Mtiles);
    // Layer 2
    spmm_csr<<<spmm_blocks, 256, 0, stream>>>(Y, row_off, csr_src, out_inv, in_inv, Xhi, Xlo, NNODES);
    gemm_mfma<1><<<gemm_blocks, 256, 0, stream>>>(Xhi, Xlo, WThi + 2 * DH * DH, WTlo + 2 * DH * DH, b2, Y, Mtiles);
    // Layer 3: project to O=10 first, then aggregate 10-wide
    proj_out<<<512, 256, 0, stream>>>(Y, out_inv, W3, Z, NNODES);
    agg10<<<(NNODES + 255) / 256, 256, 0, stream>>>(Z, row_off, csr_src, in_inv, b3, out, NNODES);
}

// Round 7
// 362.397 us; speedup vs baseline: 6.8554x; 1.1838x over previous
//
#include <hip/hip_runtime.h>

#define NNODES 50000
#define NEDGES 600000
#define DH 128
#define SCAN_THREADS 512
#define SCAN_ELEMS 2048                      // per block: 512 thr x 4
#define SCAN_BLOCKS ((NNODES + SCAN_ELEMS - 1) / SCAN_ELEMS)   // 25

typedef __attribute__((ext_vector_type(8))) short bf16x8;
typedef __attribute__((ext_vector_type(4))) float f32x4;

__device__ __forceinline__ ushort f2bf(float x) {
    uint u = __float_as_uint(x);
    uint r = (u + 0x7FFF + ((u >> 16) & 1)) >> 16;
    return (ushort)r;
}
__device__ __forceinline__ float bf2f(ushort h) {
    return __uint_as_float(((uint)h) << 16);
}

// ---------------- degree count (int atomics) ----------------
__global__ void deg_count(const int* __restrict__ src, const int* __restrict__ dst,
                          int* __restrict__ cnt_out, int* __restrict__ cnt_in, int E) {
    int i = blockIdx.x * blockDim.x + threadIdx.x;
    if (i < E) {
        atomicAdd(&cnt_out[src[i]], 1);
        atomicAdd(&cnt_in[dst[i]], 1);
    }
}

// ---------------- multi-block scan, phase 1: per-block sums ----------------
__global__ __launch_bounds__(SCAN_THREADS) void scan_sums(
        const int* __restrict__ counts, int* __restrict__ bsums, int N) {
    __shared__ int red[SCAN_THREADS / 64];
    int b = blockIdx.x, t = threadIdx.x;
    int base = b * SCAN_ELEMS + t * 4;
    int s = 0;
    if (base + 3 < N) {
        int4 v = *(const int4*)(counts + base);
        s = v.x + v.y + v.z + v.w;
    } else {
        for (int j = 0; j < 4; ++j) if (base + j < N) s += counts[base + j];
    }
#pragma unroll
    for (int off = 32; off > 0; off >>= 1) s += __shfl_down(s, off);
    if ((t & 63) == 0) red[t >> 6] = s;
    __syncthreads();
    if (t == 0) {
        int tot = 0;
#pragma unroll
        for (int w = 0; w < SCAN_THREADS / 64; ++w) tot += red[w];
        bsums[b] = tot;
    }
}

// ---------------- multi-block scan, phase 2: final exclusive offsets ----------------
__global__ __launch_bounds__(SCAN_THREADS) void scan_final(
        const int* __restrict__ counts, const int* __restrict__ bsums,
        int* __restrict__ off, int N, int nb) {
    __shared__ int lds[SCAN_THREADS];
    __shared__ int base_s;
    int b = blockIdx.x, t = threadIdx.x;
    if (t == 0) {
        int acc = 0;
        for (int i = 0; i < b; ++i) acc += bsums[i];
        base_s = acc;
    }
    int i0 = b * SCAN_ELEMS + t * 4;
    int v[4]; int s = 0;
#pragma unroll
    for (int j = 0; j < 4; ++j) {
        int idx = i0 + j;
        v[j] = (idx < N) ? counts[idx] : 0;
        s += v[j];
    }
    lds[t] = s;
    __syncthreads();
    for (int d = 1; d < SCAN_THREADS; d <<= 1) {
        int x = lds[t];
        int y = (t >= d) ? lds[t - d] : 0;
        __syncthreads();
        lds[t] = x + y;
        __syncthreads();
    }
    int excl = (t == 0) ? 0 : lds[t - 1];
    int run = base_s + excl;
#pragma unroll
    for (int j = 0; j < 4; ++j) {
        int idx = i0 + j;
        if (idx < N) off[idx] = run;
        run += v[j];
    }
    if (b == nb - 1 && t == SCAN_THREADS - 1) off[N] = run;
}

// ---------------- norms + cursor init ----------------
__global__ void inv_kernel(const int* __restrict__ cnt_out, const int* __restrict__ cnt_in,
                           const int* __restrict__ row_off, int* __restrict__ cursor,
                           float* __restrict__ out_inv, float* __restrict__ in_inv, int N) {
    int i = blockIdx.x * blockDim.x + threadIdx.x;
    if (i < N) {
        out_inv[i] = rsqrtf(fmaxf((float)cnt_out[i], 1.0f));
        in_inv[i]  = rsqrtf(fmaxf((float)cnt_in[i], 1.0f));
        cursor[i]  = row_off[i];
    }
}

// ---------------- scatter edges into dst-CSR ----------------
__global__ void scatter_kernel(const int* __restrict__ src, const int* __restrict__ dst,
                               int* __restrict__ cursor, int* __restrict__ csr_src, int E) {
    int i = blockIdx.x * blockDim.x + threadIdx.x;
    if (i < E) {
        int pos = atomicAdd(&cursor[dst[i]], 1);
        csr_src[pos] = src[i];
    }
}

// ---------------- W -> transposed bf16 hi/lo: WT[n][k] ----------------
__global__ void wconv(const float* __restrict__ W0, const float* __restrict__ W1,
                      const float* __restrict__ W2,
                      ushort* __restrict__ WThi, ushort* __restrict__ WTlo) {
    int t = blockIdx.x * blockDim.x + threadIdx.x;
    if (t >= 3 * DH * DH) return;
    int L = t >> 14;
    int idx = t & (DH * DH - 1);
    int n = idx >> 7;
    int k = idx & 127;
    const float* W = (L == 0) ? W0 : ((L == 1) ? W1 : W2);
    float w = W[k * DH + n];
    ushort hi = f2bf(w);
    float lof = w - bf2f(hi);
    WThi[t] = hi;              // t = L*16384 + n*128 + k
    WTlo[t] = f2bf(lof);
}

// ---------------- SpMM (gather), half-wave per dst row ----------------
// agg[d] = in_inv[d] * sum_{s in N(d)} out_inv[s]*h[s]; emits bf16 hi/lo
__global__ __launch_bounds__(256) void spmm_csr(
        const float* __restrict__ h, const int* __restrict__ row_off,
        const int* __restrict__ csr_src, const float* __restrict__ out_inv,
        const float* __restrict__ in_inv,
        ushort* __restrict__ Xhi, ushort* __restrict__ Xlo, int N) {
    int gw   = (blockIdx.x * blockDim.x + threadIdx.x) >> 6;
    int lane = threadIdx.x & 63;
    int half = lane >> 5;          // two rows per wave
    int l5   = lane & 31;          // 32 lanes x float4 = 512B row
    int row  = gw * 2 + half;
    if (row >= N) return;
    int start = row_off[row], end = row_off[row + 1];
    float4 acc = make_float4(0.f, 0.f, 0.f, 0.f);
    for (int e = start; e < end; ++e) {
        int s = csr_src[e];
        float sc = out_inv[s];
        float4 v = ((const float4*)(h + (size_t)s * DH))[l5];
        acc.x += v.x * sc; acc.y += v.y * sc;
        acc.z += v.z * sc; acc.w += v.w * sc;
    }
    float ii = in_inv[row];
    acc.x *= ii; acc.y *= ii; acc.z *= ii; acc.w *= ii;

    ushort4 hi, lo;
    hi.x = f2bf(acc.x); lo.x = f2bf(acc.x - bf2f(hi.x));
    hi.y = f2bf(acc.y); lo.y = f2bf(acc.y - bf2f(hi.y));
    hi.z = f2bf(acc.z); lo.z = f2bf(acc.z - bf2f(hi.z));
    hi.w = f2bf(acc.w); lo.w = f2bf(acc.w - bf2f(hi.w));
    ((ushort4*)(Xhi + (size_t)row * DH))[l5] = hi;
    ((ushort4*)(Xlo + (size_t)row * DH))[l5] = lo;
}

// ---------------- MFMA GEMM: Y = relu(X @ W + b), split-bf16 3-pass ----------------
template<int RELU>
__global__ __launch_bounds__(256, 2) void gemm_mfma(
        const ushort* __restrict__ Xhi, const ushort* __restrict__ Xlo,
        const ushort* __restrict__ WThi, const ushort* __restrict__ WTlo,
        const float* __restrict__ bias, float* __restrict__ Y, int Mtiles) {
    int lane  = threadIdx.x & 63;
    int gwave = (blockIdx.x * blockDim.x + threadIdx.x) >> 6;
    int nwav  = (gridDim.x * blockDim.x) >> 6;
    int nhalf = gwave & 1;          // col half: 0 -> 0..63, 1 -> 64..127
    int wstart  = gwave >> 1;
    int wstride = nwav >> 1;

    int r  = lane & 15;             // A-row / B-col / D-col within tile
    int kq = lane >> 4;             // k quarter within a K=32 fragment

    // persistent B fragments: [hi/lo][ntile][kfrag]
    bf16x8 B[2][4][4];
#pragma unroll
    for (int nt = 0; nt < 4; ++nt) {
        int n = 64 * nhalf + 16 * nt + r;
#pragma unroll
        for (int kf = 0; kf < 4; ++kf) {
            B[0][nt][kf] = *(const bf16x8*)(WThi + n * DH + 32 * kf + 8 * kq);
            B[1][nt][kf] = *(const bf16x8*)(WTlo + n * DH + 32 * kf + 8 * kq);
        }
    }
    float bs[4];
#pragma unroll
    for (int nt = 0; nt < 4; ++nt) bs[nt] = bias[64 * nhalf + 16 * nt + r];

    for (int mt = wstart; mt < Mtiles; mt += wstride) {
        int m0 = mt * 16;
        const ushort* xh = Xhi + (size_t)(m0 + r) * DH + 8 * kq;
        const ushort* xl = Xlo + (size_t)(m0 + r) * DH + 8 * kq;
        bf16x8 Ah[4], Al[4];
#pragma unroll
        for (int kf = 0; kf < 4; ++kf) {
            Ah[kf] = *(const bf16x8*)(xh + 32 * kf);
            Al[kf] = *(const bf16x8*)(xl + 32 * kf);
        }
        f32x4 acc[4];
#pragma unroll
        for (int nt = 0; nt < 4; ++nt)
            acc[nt] = (f32x4){bs[nt], bs[nt], bs[nt], bs[nt]};
#pragma unroll
        for (int kf = 0; kf < 4; ++kf) {
#pragma unroll
            for (int nt = 0; nt < 4; ++nt) {
                acc[nt] = __builtin_amdgcn_mfma_f32_16x16x32_bf16(Ah[kf], B[0][nt][kf], acc[nt], 0, 0, 0);
                acc[nt] = __builtin_amdgcn_mfma_f32_16x16x32_bf16(Ah[kf], B[1][nt][kf], acc[nt], 0, 0, 0);
                acc[nt] = __builtin_amdgcn_mfma_f32_16x16x32_bf16(Al[kf], B[0][nt][kf], acc[nt], 0, 0, 0);
            }
        }
        // D: row = m0 + 4*kq + j, col = 64*nhalf + 16*nt + r
#pragma unroll
        for (int nt = 0; nt < 4; ++nt) {
            int n = 64 * nhalf + 16 * nt + r;
            float* yp = Y + (size_t)(m0 + 4 * kq) * DH + n;
#pragma unroll
            for (int j = 0; j < 4; ++j) {
                float v = acc[nt][j];
                if (RELU) v = fmaxf(v, 0.f);
                yp[(size_t)j * DH] = v;
            }
        }
    }
}

// ---------------- layer-3 projection: Z = (X * out_inv) @ W3   (N x 10) ----------------
__global__ __launch_bounds__(256) void proj_out(
        const float* __restrict__ X, const float* __restrict__ out_inv,
        const float* __restrict__ W, float* __restrict__ Z, int N) {
    __shared__ float Wl[DH * 10];
    for (int i = threadIdx.x; i < DH * 10; i += blockDim.x) Wl[i] = W[i];
    __syncthreads();

    int lane = threadIdx.x & 63;
    int wid  = threadIdx.x >> 6;
    int wpb  = blockDim.x >> 6;
    int gw   = blockIdx.x * wpb + wid;
    int nw   = gridDim.x * wpb;

    for (int row = gw; row < N; row += nw) {
        float sc = out_inv[row];
        float2 x = ((const float2*)(X + (size_t)row * DH))[lane];
        x.x *= sc; x.y *= sc;
        float acc[10];
#pragma unroll
        for (int o = 0; o < 10; ++o)
            acc[o] = x.x * Wl[(2 * lane) * 10 + o] + x.y * Wl[(2 * lane + 1) * 10 + o];
#pragma unroll
        for (int off = 32; off > 0; off >>= 1) {
#pragma unroll
            for (int o = 0; o < 10; ++o)
                acc[o] += __shfl_down(acc[o], off);
        }
        if (lane == 0) {
#pragma unroll
            for (int o = 0; o < 10; ++o)
                Z[(size_t)row * 10 + o] = acc[o];
        }
    }
}

// ---------------- layer-3 aggregation: out[d] = in_inv[d]*sum Z[s] + b3 ----------------
__global__ void agg10(const float* __restrict__ Z, const int* __restrict__ row_off,
                      const int* __restrict__ csr_src, const float* __restrict__ in_inv,
                      const float* __restrict__ b, float* __restrict__ out, int N) {
    int r = blockIdx.x * blockDim.x + threadIdx.x;
    if (r >= N) return;
    float2 acc[5] = {};
    int start = row_off[r], end = row_off[r + 1];
    for (int e = start; e < end; ++e) {
        int s = csr_src[e];
        const float2* zp = (const float2*)(Z + (size_t)s * 10);
#pragma unroll
        for (int o = 0; o < 5; ++o) {
            float2 z = zp[o];
            acc[o].x += z.x; acc[o].y += z.y;
        }
    }
    float ii = in_inv[r];
#pragma unroll
    for (int o = 0; o < 5; ++o) {
        out[(size_t)r * 10 + 2 * o]     = acc[o].x * ii + b[2 * o];
        out[(size_t)r * 10 + 2 * o + 1] = acc[o].y * ii + b[2 * o + 1];
    }
}

extern "C" void kernel_launch(void* const* d_in, const int* in_sizes, int n_in,
                              void* d_out, int out_size, void* d_ws, size_t ws_size,
                              hipStream_t stream) {
    const float* features = (const float*)d_in[0];
    const int*   src      = (const int*)d_in[1];
    const int*   dst      = (const int*)d_in[2];
    const float* W0 = (const float*)d_in[3];
    const float* b0 = (const float*)d_in[4];
    const float* W1 = (const float*)d_in[5];
    const float* b1 = (const float*)d_in[6];
    const float* W2 = (const float*)d_in[7];
    const float* b2 = (const float*)d_in[8];
    const float* W3 = (const float*)d_in[9];
    const float* b3 = (const float*)d_in[10];
    float* out = (float*)d_out;

    char* ws = (char*)d_ws;
    int*   cnt_out = (int*)ws;                       // N
    int*   cnt_in  = cnt_out + NNODES;               // N
    int*   cursor  = cnt_in + NNODES;                // N
    int*   row_off = cursor + NNODES;                // N+1
    int*   bsums   = row_off + NNODES + 1;           // SCAN_BLOCKS
    float* out_inv = (float*)(bsums + SCAN_BLOCKS);  // N
    float* in_inv  = out_inv + NNODES;               // N
    int*   csr_src = (int*)(in_inv + NNODES);        // E
    size_t metaInts = (size_t)(6 * NNODES + 1 + SCAN_BLOCKS) + NEDGES;
    size_t off = ((metaInts * 4 + 255) / 256) * 256;
    ushort* WThi = (ushort*)(ws + off);  off += 3 * DH * DH * sizeof(ushort);
    ushort* WTlo = (ushort*)(ws + off);  off += 3 * DH * DH * sizeof(ushort);
    off = ((off + 255) / 256) * 256;
    ushort* Xhi = (ushort*)(ws + off);   off += (size_t)NNODES * DH * sizeof(ushort);
    ushort* Xlo = (ushort*)(ws + off);   off += (size_t)NNODES * DH * sizeof(ushort);
    float*  Y   = (float*)(ws + off);    off += (size_t)NNODES * DH * sizeof(float);
    float*  Z   = (float*)Xhi;           // reused for layer-3 projection (N x 10)

    // ---- CSR build + norms + W conversion (once per call) ----
    hipMemsetAsync(cnt_out, 0, 2 * NNODES * sizeof(int), stream);
    deg_count<<<(NEDGES + 255) / 256, 256, 0, stream>>>(src, dst, cnt_out, cnt_in, NEDGES);
    scan_sums<<<SCAN_BLOCKS, SCAN_THREADS, 0, stream>>>(cnt_in, bsums, NNODES);
    scan_final<<<SCAN_BLOCKS, SCAN_THREADS, 0, stream>>>(cnt_in, bsums, row_off, NNODES, SCAN_BLOCKS);
    inv_kernel<<<(NNODES + 255) / 256, 256, 0, stream>>>(cnt_out, cnt_in, row_off, cursor, out_inv, in_inv, NNODES);
    scatter_kernel<<<(NEDGES + 255) / 256, 256, 0, stream>>>(src, dst, cursor, csr_src, NEDGES);
    wconv<<<(3 * DH * DH + 255) / 256, 256, 0, stream>>>(W0, W1, W2, WThi, WTlo);

    const int spmm_blocks = (NNODES / 2 + 3) / 4;   // half-wave per row, 4 waves/block
    const int Mtiles = NNODES / 16;                 // 3125
    const int gemm_blocks = 512;                    // 2048 waves, persistent B-frags

    // Layer 0
    spmm_csr<<<spmm_blocks, 256, 0, stream>>>(features, row_off, csr_src, out_inv, in_inv, Xhi, Xlo, NNODES);
    gemm_mfma<1><<<gemm_blocks, 256, 0, stream>>>(Xhi, Xlo, WThi, WTlo, b0, Y, Mtiles);
    // Layer 1
    spmm_csr<<<spmm_blocks, 256, 0, stream>>>(Y, row_off, csr_src, out_inv, in_inv, Xhi, Xlo, NNODES);
    gemm_mfma<1><<<gemm_blocks, 256, 0, stream>>>(Xhi, Xlo, WThi + DH * DH, WTlo + DH * DH, b1, Y, Mtiles);
    // Layer 2
    spmm_csr<<<spmm_blocks, 256, 0, stream>>>(Y, row_off, csr_src, out_inv, in_inv, Xhi, Xlo, NNODES);
    gemm_mfma<1><<<gemm_blocks, 256, 0, stream>>>(Xhi, Xlo, WThi + 2 * DH * DH, WTlo + 2 * DH * DH, b2, Y, Mtiles);
    // Layer 3: project to O=10 first, then aggregate 10-wide
    proj_out<<<512, 256, 0, stream>>>(Y, out_inv, W3, Z, NNODES);
    agg10<<<(NNODES + 255) / 256, 256, 0, stream>>>(Z, row_off, csr_src, in_inv, b3, out, NNODES);
}

// Round 10
// 310.309 us; speedup vs baseline: 8.0062x; 1.1679x over previous
//
#include <hip/hip_runtime.h>

#define NNODES 50000
#define NEDGES 600000
#define DH 128
#define SCAN_THREADS 512
#define SCAN_ELEMS 2048
#define SCAN_BLOCKS ((NNODES + SCAN_ELEMS - 1) / SCAN_ELEMS)   // 25

typedef __attribute__((ext_vector_type(8))) short bf16x8;
typedef __attribute__((ext_vector_type(4))) float f32x4;
typedef __attribute__((ext_vector_type(4))) _Float16 half4;
typedef __attribute__((ext_vector_type(2))) _Float16 half2v;

__device__ __forceinline__ ushort f2bf(float x) {
    uint u = __float_as_uint(x);
    uint r = (u + 0x7FFF + ((u >> 16) & 1)) >> 16;
    return (ushort)r;
}
__device__ __forceinline__ float bf2f(ushort h) {
    return __uint_as_float(((uint)h) << 16);
}

// ---------------- degree count (int atomics) ----------------
__global__ void deg_count(const int* __restrict__ src, const int* __restrict__ dst,
                          int* __restrict__ cnt_out, int* __restrict__ cnt_in, int E) {
    int i = blockIdx.x * blockDim.x + threadIdx.x;
    if (i < E) {
        atomicAdd(&cnt_out[src[i]], 1);
        atomicAdd(&cnt_in[dst[i]], 1);
    }
}

// ---------------- multi-block scan, phase 1: per-block sums ----------------
__global__ __launch_bounds__(SCAN_THREADS) void scan_sums(
        const int* __restrict__ counts, int* __restrict__ bsums, int N) {
    __shared__ int red[SCAN_THREADS / 64];
    int b = blockIdx.x, t = threadIdx.x;
    int base = b * SCAN_ELEMS + t * 4;
    int s = 0;
    if (base + 3 < N) {
        int4 v = *(const int4*)(counts + base);
        s = v.x + v.y + v.z + v.w;
    } else {
        for (int j = 0; j < 4; ++j) if (base + j < N) s += counts[base + j];
    }
#pragma unroll
    for (int off = 32; off > 0; off >>= 1) s += __shfl_down(s, off);
    if ((t & 63) == 0) red[t >> 6] = s;
    __syncthreads();
    if (t == 0) {
        int tot = 0;
#pragma unroll
        for (int w = 0; w < SCAN_THREADS / 64; ++w) tot += red[w];
        bsums[b] = tot;
    }
}

// ---------------- multi-block scan, phase 2: final exclusive offsets ----------------
__global__ __launch_bounds__(SCAN_THREADS) void scan_final(
        const int* __restrict__ counts, const int* __restrict__ bsums,
        int* __restrict__ off, int N, int nb) {
    __shared__ int lds[SCAN_THREADS];
    __shared__ int base_s;
    int b = blockIdx.x, t = threadIdx.x;
    if (t == 0) {
        int acc = 0;
        for (int i = 0; i < b; ++i) acc += bsums[i];
        base_s = acc;
    }
    int i0 = b * SCAN_ELEMS + t * 4;
    int v[4]; int s = 0;
#pragma unroll
    for (int j = 0; j < 4; ++j) {
        int idx = i0 + j;
        v[j] = (idx < N) ? counts[idx] : 0;
        s += v[j];
    }
    lds[t] = s;
    __syncthreads();
    for (int d = 1; d < SCAN_THREADS; d <<= 1) {
        int x = lds[t];
        int y = (t >= d) ? lds[t - d] : 0;
        __syncthreads();
        lds[t] = x + y;
        __syncthreads();
    }
    int excl = (t == 0) ? 0 : lds[t - 1];
    int run = base_s + excl;
#pragma unroll
    for (int j = 0; j < 4; ++j) {
        int idx = i0 + j;
        if (idx < N) off[idx] = run;
        run += v[j];
    }
    if (b == nb - 1 && t == SCAN_THREADS - 1) off[N] = run;
}

// ---------------- norms + cursor init ----------------
__global__ void inv_kernel(const int* __restrict__ cnt_out, const int* __restrict__ cnt_in,
                           const int* __restrict__ row_off, int* __restrict__ cursor,
                           float* __restrict__ out_inv, float* __restrict__ in_inv, int N) {
    int i = blockIdx.x * blockDim.x + threadIdx.x;
    if (i < N) {
        out_inv[i] = rsqrtf(fmaxf((float)cnt_out[i], 1.0f));
        in_inv[i]  = rsqrtf(fmaxf((float)cnt_in[i], 1.0f));
        cursor[i]  = row_off[i];
    }
}

// ---------------- scatter edges into dst-CSR ----------------
__global__ void scatter_kernel(const int* __restrict__ src, const int* __restrict__ dst,
                               int* __restrict__ cursor, int* __restrict__ csr_src, int E) {
    int i = blockIdx.x * blockDim.x + threadIdx.x;
    if (i < E) {
        int pos = atomicAdd(&cursor[dst[i]], 1);
        csr_src[pos] = src[i];
    }
}

// ---------------- W -> transposed bf16 hi/lo: WT[n][k] ----------------
__global__ void wconv(const float* __restrict__ W0, const float* __restrict__ W1,
                      const float* __restrict__ W2,
                      ushort* __restrict__ WThi, ushort* __restrict__ WTlo) {
    int t = blockIdx.x * blockDim.x + threadIdx.x;
    if (t >= 3 * DH * DH) return;
    int L = t >> 14;
    int idx = t & (DH * DH - 1);
    int n = idx >> 7;
    int k = idx & 127;
    const float* W = (L == 0) ? W0 : ((L == 1) ? W1 : W2);
    float w = W[k * DH + n];
    ushort hi = f2bf(w);
    float lof = w - bf2f(hi);
    WThi[t] = hi;
    WTlo[t] = f2bf(lof);
}

// ---------------- features fp32 -> fp16 ----------------
__global__ void f32_to_f16(const float* __restrict__ in, _Float16* __restrict__ out, int n4) {
    int i = blockIdx.x * blockDim.x + threadIdx.x;
    if (i < n4) {
        float4 v = ((const float4*)in)[i];
        half4 h = {(_Float16)v.x, (_Float16)v.y, (_Float16)v.z, (_Float16)v.w};
        ((half4*)out)[i] = h;
    }
}

// ---------------- SpMM (gather fp16), half-wave per dst row, unroll x2 ----------------
// agg[d] = in_inv[d] * sum_{s in N(d)} out_inv[s]*h[s]; emits split-bf16
__global__ __launch_bounds__(256) void spmm_csr(
        const _Float16* __restrict__ h, const int* __restrict__ row_off,
        const int* __restrict__ csr_src, const float* __restrict__ out_inv,
        const float* __restrict__ in_inv,
        ushort* __restrict__ Xhi, ushort* __restrict__ Xlo, int N) {
    int gw   = (blockIdx.x * blockDim.x + threadIdx.x) >> 6;
    int lane = threadIdx.x & 63;
    int half = lane >> 5;          // two rows per wave
    int l5   = lane & 31;          // 32 lanes x 8B = 256B row
    int row  = gw * 2 + half;
    if (row >= N) return;
    int start = row_off[row], end = row_off[row + 1];
    float4 acc0 = make_float4(0.f, 0.f, 0.f, 0.f);
    float4 acc1 = make_float4(0.f, 0.f, 0.f, 0.f);
    int e = start;
    for (; e + 2 <= end; e += 2) {
        int s0 = csr_src[e];
        int s1 = csr_src[e + 1];
        float sc0 = out_inv[s0];
        float sc1 = out_inv[s1];
        half4 v0 = ((const half4*)(h + (size_t)s0 * DH))[l5];
        half4 v1 = ((const half4*)(h + (size_t)s1 * DH))[l5];
        acc0.x += (float)v0.x * sc0; acc0.y += (float)v0.y * sc0;
        acc0.z += (float)v0.z * sc0; acc0.w += (float)v0.w * sc0;
        acc1.x += (float)v1.x * sc1; acc1.y += (float)v1.y * sc1;
        acc1.z += (float)v1.z * sc1; acc1.w += (float)v1.w * sc1;
    }
    if (e < end) {
        int s0 = csr_src[e];
        float sc0 = out_inv[s0];
        half4 v0 = ((const half4*)(h + (size_t)s0 * DH))[l5];
        acc0.x += (float)v0.x * sc0; acc0.y += (float)v0.y * sc0;
        acc0.z += (float)v0.z * sc0; acc0.w += (float)v0.w * sc0;
    }
    float ii = in_inv[row];
    float4 acc;
    acc.x = (acc0.x + acc1.x) * ii;
    acc.y = (acc0.y + acc1.y) * ii;
    acc.z = (acc0.z + acc1.z) * ii;
    acc.w = (acc0.w + acc1.w) * ii;

    ushort4 hi, lo;
    hi.x = f2bf(acc.x); lo.x = f2bf(acc.x - bf2f(hi.x));
    hi.y = f2bf(acc.y); lo.y = f2bf(acc.y - bf2f(hi.y));
    hi.z = f2bf(acc.z); lo.z = f2bf(acc.z - bf2f(hi.z));
    hi.w = f2bf(acc.w); lo.w = f2bf(acc.w - bf2f(hi.w));
    ((ushort4*)(Xhi + (size_t)row * DH))[l5] = hi;
    ((ushort4*)(Xlo + (size_t)row * DH))[l5] = lo;
}

// ---------------- MFMA GEMM: Yf16 = relu(X @ W + b), split-bf16 3-pass ----------------
template<int RELU>
__global__ __launch_bounds__(256, 2) void gemm_mfma(
        const ushort* __restrict__ Xhi, const ushort* __restrict__ Xlo,
        const ushort* __restrict__ WThi, const ushort* __restrict__ WTlo,
        const float* __restrict__ bias, _Float16* __restrict__ Y, int Mtiles) {
    int lane  = threadIdx.x & 63;
    int gwave = (blockIdx.x * blockDim.x + threadIdx.x) >> 6;
    int nwav  = (gridDim.x * blockDim.x) >> 6;
    int nhalf = gwave & 1;
    int wstart  = gwave >> 1;
    int wstride = nwav >> 1;

    int r  = lane & 15;
    int kq = lane >> 4;

    bf16x8 B[2][4][4];
#pragma unroll
    for (int nt = 0; nt < 4; ++nt) {
        int n = 64 * nhalf + 16 * nt + r;
#pragma unroll
        for (int kf = 0; kf < 4; ++kf) {
            B[0][nt][kf] = *(const bf16x8*)(WThi + n * DH + 32 * kf + 8 * kq);
            B[1][nt][kf] = *(const bf16x8*)(WTlo + n * DH + 32 * kf + 8 * kq);
        }
    }
    float bs[4];
#pragma unroll
    for (int nt = 0; nt < 4; ++nt) bs[nt] = bias[64 * nhalf + 16 * nt + r];

    for (int mt = wstart; mt < Mtiles; mt += wstride) {
        int m0 = mt * 16;
        const ushort* xh = Xhi + (size_t)(m0 + r) * DH + 8 * kq;
        const ushort* xl = Xlo + (size_t)(m0 + r) * DH + 8 * kq;
        bf16x8 Ah[4], Al[4];
#pragma unroll
        for (int kf = 0; kf < 4; ++kf) {
            Ah[kf] = *(const bf16x8*)(xh + 32 * kf);
            Al[kf] = *(const bf16x8*)(xl + 32 * kf);
        }
        f32x4 acc[4];
#pragma unroll
        for (int nt = 0; nt < 4; ++nt)
            acc[nt] = (f32x4){bs[nt], bs[nt], bs[nt], bs[nt]};
#pragma unroll
        for (int kf = 0; kf < 4; ++kf) {
#pragma unroll
            for (int nt = 0; nt < 4; ++nt) {
                acc[nt] = __builtin_amdgcn_mfma_f32_16x16x32_bf16(Ah[kf], B[0][nt][kf], acc[nt], 0, 0, 0);
                acc[nt] = __builtin_amdgcn_mfma_f32_16x16x32_bf16(Ah[kf], B[1][nt][kf], acc[nt], 0, 0, 0);
                acc[nt] = __builtin_amdgcn_mfma_f32_16x16x32_bf16(Al[kf], B[0][nt][kf], acc[nt], 0, 0, 0);
            }
        }
        // D: row = m0 + 4*kq + j, col = 64*nhalf + 16*nt + r
#pragma unroll
        for (int nt = 0; nt < 4; ++nt) {
            int n = 64 * nhalf + 16 * nt + r;
            _Float16* yp = Y + (size_t)(m0 + 4 * kq) * DH + n;
#pragma unroll
            for (int j = 0; j < 4; ++j) {
                float v = acc[nt][j];
                if (RELU) v = fmaxf(v, 0.f);
                yp[(size_t)j * DH] = (_Float16)v;
            }
        }
    }
}

// ---------------- layer-3 projection: Z = (X * out_inv) @ W3   (N x 10) ----------------
__global__ __launch_bounds__(256) void proj_out(
        const _Float16* __restrict__ X, const float* __restrict__ out_inv,
        const float* __restrict__ W, float* __restrict__ Z, int N) {
    __shared__ float Wl[DH * 10];
    for (int i = threadIdx.x; i < DH * 10; i += blockDim.x) Wl[i] = W[i];
    __syncthreads();

    int lane = threadIdx.x & 63;
    int wid  = threadIdx.x >> 6;
    int wpb  = blockDim.x >> 6;
    int gw   = blockIdx.x * wpb + wid;
    int nw   = gridDim.x * wpb;

    for (int row = gw; row < N; row += nw) {
        float sc = out_inv[row];
        half2v xh = ((const half2v*)(X + (size_t)row * DH))[lane];
        float xx = (float)xh.x * sc;
        float xy = (float)xh.y * sc;
        float acc[10];
#pragma unroll
        for (int o = 0; o < 10; ++o)
            acc[o] = xx * Wl[(2 * lane) * 10 + o] + xy * Wl[(2 * lane + 1) * 10 + o];
#pragma unroll
        for (int off = 32; off > 0; off >>= 1) {
#pragma unroll
            for (int o = 0; o < 10; ++o)
                acc[o] += __shfl_down(acc[o], off);
        }
        if (lane == 0) {
#pragma unroll
            for (int o = 0; o < 10; ++o)
                Z[(size_t)row * 10 + o] = acc[o];
        }
    }
}

// ---------------- layer-3 aggregation: out[d] = in_inv[d]*sum Z[s] + b3 ----------------
__global__ void agg10(const float* __restrict__ Z, const int* __restrict__ row_off,
                      const int* __restrict__ csr_src, const float* __restrict__ in_inv,
                      const float* __restrict__ b, float* __restrict__ out, int N) {
    int r = blockIdx.x * blockDim.x + threadIdx.x;
    if (r >= N) return;
    float2 acc[5] = {};
    int start = row_off[r], end = row_off[r + 1];
    for (int e = start; e < end; ++e) {
        int s = csr_src[e];
        const float2* zp = (const float2*)(Z + (size_t)s * 10);
#pragma unroll
        for (int o = 0; o < 5; ++o) {
            float2 z = zp[o];
            acc[o].x += z.x; acc[o].y += z.y;
        }
    }
    float ii = in_inv[r];
#pragma unroll
    for (int o = 0; o < 5; ++o) {
        out[(size_t)r * 10 + 2 * o]     = acc[o].x * ii + b[2 * o];
        out[(size_t)r * 10 + 2 * o + 1] = acc[o].y * ii + b[2 * o + 1];
    }
}

extern "C" void kernel_launch(void* const* d_in, const int* in_sizes, int n_in,
                              void* d_out, int out_size, void* d_ws, size_t ws_size,
                              hipStream_t stream) {
    const float* features = (const float*)d_in[0];
    const int*   src      = (const int*)d_in[1];
    const int*   dst      = (const int*)d_in[2];
    const float* W0 = (const float*)d_in[3];
    const float* b0 = (const float*)d_in[4];
    const float* W1 = (const float*)d_in[5];
    const float* b1 = (const float*)d_in[6];
    const float* W2 = (const float*)d_in[7];
    const float* b2 = (const float*)d_in[8];
    const float* W3 = (const float*)d_in[9];
    const float* b3 = (const float*)d_in[10];
    float* out = (float*)d_out;

    char* ws = (char*)d_ws;
    int*   cnt_out = (int*)ws;                       // N
    int*   cnt_in  = cnt_out + NNODES;               // N
    int*   cursor  = cnt_in + NNODES;                // N
    int*   row_off = cursor + NNODES;                // N+1
    int*   bsums   = row_off + NNODES + 1;           // SCAN_BLOCKS
    float* out_inv = (float*)(bsums + SCAN_BLOCKS);  // N
    float* in_inv  = out_inv + NNODES;               // N
    int*   csr_src = (int*)(in_inv + NNODES);        // E
    size_t metaInts = (size_t)(6 * NNODES + 1 + SCAN_BLOCKS) + NEDGES;
    size_t off = ((metaInts * 4 + 255) / 256) * 256;
    ushort* WThi = (ushort*)(ws + off);  off += 3 * DH * DH * sizeof(ushort);
    ushort* WTlo = (ushort*)(ws + off);  off += 3 * DH * DH * sizeof(ushort);
    off = ((off + 255) / 256) * 256;
    ushort* Xhi = (ushort*)(ws + off);     off += (size_t)NNODES * DH * sizeof(ushort);
    ushort* Xlo = (ushort*)(ws + off);     off += (size_t)NNODES * DH * sizeof(ushort);
    _Float16* F16 = (_Float16*)(ws + off); off += (size_t)NNODES * DH * sizeof(_Float16);
    _Float16* Y16 = (_Float16*)(ws + off); off += (size_t)NNODES * DH * sizeof(_Float16);
    float*  Z   = (float*)Xhi;             // reused for layer-3 projection (N x 10)

    // ---- CSR build + norms + W conversion + feature fp16 (once per call) ----
    hipMemsetAsync(cnt_out, 0, 2 * NNODES * sizeof(int), stream);
    deg_count<<<(NEDGES + 255) / 256, 256, 0, stream>>>(src, dst, cnt_out, cnt_in, NEDGES);
    scan_sums<<<SCAN_BLOCKS, SCAN_THREADS, 0, stream>>>(cnt_in, bsums, NNODES);
    scan_final<<<SCAN_BLOCKS, SCAN_THREADS, 0, stream>>>(cnt_in, bsums, row_off, NNODES, SCAN_BLOCKS);
    inv_kernel<<<(NNODES + 255) / 256, 256, 0, stream>>>(cnt_out, cnt_in, row_off, cursor, out_inv, in_inv, NNODES);
    scatter_kernel<<<(NEDGES + 255) / 256, 256, 0, stream>>>(src, dst, cursor, csr_src, NEDGES);
    wconv<<<(3 * DH * DH + 255) / 256, 256, 0, stream>>>(W0, W1, W2, WThi, WTlo);
    f32_to_f16<<<(NNODES * DH / 4 + 255) / 256, 256, 0, stream>>>(features, F16, NNODES * DH / 4);

    const int spmm_blocks = (NNODES / 2 + 3) / 4;
    const int Mtiles = NNODES / 16;                 // 3125
    const int gemm_blocks = 512;

    // Layer 0
    spmm_csr<<<spmm_blocks, 256, 0, stream>>>(F16, row_off, csr_src, out_inv, in_inv, Xhi, Xlo, NNODES);
    gemm_mfma<1><<<gemm_blocks, 256, 0, stream>>>(Xhi, Xlo, WThi, WTlo, b0, Y16, Mtiles);
    // Layer 1
    spmm_csr<<<spmm_blocks, 256, 0, stream>>>(Y16, row_off, csr_src, out_inv, in_inv, Xhi, Xlo, NNODES);
    gemm_mfma<1><<<gemm_blocks, 256, 0, stream>>>(Xhi, Xlo, WThi + DH * DH, WTlo + DH * DH, b1, Y16, Mtiles);
    // Layer 2
    spmm_csr<<<spmm_blocks, 256, 0, stream>>>(Y16, row_off, csr_src, out_inv, in_inv, Xhi, Xlo, NNODES);
    gemm_mfma<1><<<gemm_blocks, 256, 0, stream>>>(Xhi, Xlo, WThi + 2 * DH * DH, WTlo + 2 * DH * DH, b2, Y16, Mtiles);
    // Layer 3: project to O=10 first, then aggregate 10-wide
    proj_out<<<512, 256, 0, stream>>>(Y16, out_inv, W3, Z, NNODES);
    agg10<<<(NNODES + 255) / 256, 256, 0, stream>>>(Z, row_off, csr_src, in_inv, b3, out, NNODES);
}